// Round 3
// baseline (1262.619 us; speedup 1.0000x reference)
//
#include <hip/hip_runtime.h>

#define N_NODES 100000
#define F 64
#define C 32
#define KH 3
#define E 1600000
#define NE (KH * E)                       // 4,800,000 edges

#define RPB 128                           // rows per coarse bucket (pow2, shift 7)
#define NBUCK ((N_NODES + RPB - 1) / RPB) // 782
#define CHUNK 4096                        // edges per partition block
#define EPT (CHUNK / 256)                 // 16 edges per thread
#define NCHUNK ((NE + CHUNK - 1) / CHUNK) // 1172
#define ECH 1024                          // edges staged per spmm inner iter

// ---------------------------------------------------------------------------
// K1: y[n, c] = sum_f x[n, f] * W[f, c]   (all fp32)
// ---------------------------------------------------------------------------
__global__ __launch_bounds__(256) void gemm_xw(const float* __restrict__ x,
                                               const float* __restrict__ W,
                                               float* __restrict__ y) {
    __shared__ float Ws[F * C];  // 8 KB
    for (int i = threadIdx.x; i < F * C; i += 256) Ws[i] = W[i];
    __syncthreads();

    const int node = blockIdx.x * 256 + threadIdx.x;
    if (node >= N_NODES) return;

    const float4* xp = (const float4*)(x + (size_t)node * F);
    float acc[C];
#pragma unroll
    for (int c = 0; c < C; c++) acc[c] = 0.f;

#pragma unroll
    for (int i = 0; i < 16; i++) {
        float4 v = xp[i];
        const int f = i * 4;
#pragma unroll
        for (int c = 0; c < C; c++) {
            acc[c] += v.x * Ws[(f + 0) * C + c];
            acc[c] += v.y * Ws[(f + 1) * C + c];
            acc[c] += v.z * Ws[(f + 2) * C + c];
            acc[c] += v.w * Ws[(f + 3) * C + c];
        }
    }

    float4* yo = (float4*)(y + (size_t)node * C);
#pragma unroll
    for (int i = 0; i < 8; i++)
        yo[i] = make_float4(acc[4 * i], acc[4 * i + 1], acc[4 * i + 2], acc[4 * i + 3]);
}

// ---------------------------------------------------------------------------
// K2: coarse histogram — edges per 128-row bucket. LDS-aggregated.
// ---------------------------------------------------------------------------
__global__ __launch_bounds__(256) void hist_c(const int* __restrict__ rows,
                                              int* __restrict__ hcnt) {
    __shared__ int h[NBUCK];
    for (int i = threadIdx.x; i < NBUCK; i += 256) h[i] = 0;
    __syncthreads();
    const int base = blockIdx.x * CHUNK;
#pragma unroll
    for (int j = 0; j < EPT; j++) {
        const int e = base + j * 256 + threadIdx.x;
        if (e < NE) atomicAdd(&h[rows[e] >> 7], 1);
    }
    __syncthreads();
    for (int i = threadIdx.x; i < NBUCK; i += 256) {
        const int c = h[i];
        if (c) atomicAdd(&hcnt[i], c);
    }
}

// ---------------------------------------------------------------------------
// K3: exclusive scan of the 782 bucket counts (single block).
// Writes gstart[0..NBUCK] (sentinel = NE) and initializes gcur = gstart.
// ---------------------------------------------------------------------------
__global__ __launch_bounds__(256) void scan_c(const int* __restrict__ hcnt,
                                              int* __restrict__ gstart,
                                              int* __restrict__ gcur) {
    __shared__ int sA[1024];
    __shared__ int sB[1024];
    const int tid = threadIdx.x;
    for (int i = tid; i < 1024; i += 256) sA[i] = (i < NBUCK) ? hcnt[i] : 0;
    __syncthreads();

    int* src = sA;
    int* dst = sB;
    for (int d = 1; d < 1024; d <<= 1) {   // 10 rounds -> result back in sA
        for (int i = tid; i < 1024; i += 256) {
            int v = src[i];
            if (i >= d) v += src[i - d];
            dst[i] = v;
        }
        __syncthreads();
        int* t = src; src = dst; dst = t;
    }
    // src == sA holds the inclusive scan
    for (int i = tid; i < NBUCK; i += 256) {
        const int excl = (i == 0) ? 0 : src[i - 1];
        gstart[i] = excl;
        gcur[i] = excl;
    }
    if (tid == 0) gstart[NBUCK] = NE;
}

// ---------------------------------------------------------------------------
// K4: partition — LDS-staged radix partition of edges into coarse buckets.
// Per 4096-edge chunk: LDS bin counts -> block scan -> one global atomic per
// (chunk, bin) to claim contiguous space -> coalesced flush in ~runs.
// Entry: { (row&127)<<17 | col , val*alpha } (8 B).
// ---------------------------------------------------------------------------
__global__ __launch_bounds__(256) void part_c(const float* __restrict__ vals,
                                              const int* __restrict__ rows,
                                              const int* __restrict__ cols,
                                              const float* __restrict__ alpha,
                                              int* __restrict__ gcur,
                                              int2* __restrict__ edgebuf) {
    __shared__ int sA[1024];              // counts -> inclusive scan
    __shared__ int sB[1024];              // scan scratch
    __shared__ int lpos[NBUCK];           // running placement cursor
    __shared__ int lbase[NBUCK];          // claimed global base
    __shared__ int2 stage[CHUNK];         // 32 KB
    __shared__ unsigned short sbin[CHUNK];// 8 KB

    const int tid = threadIdx.x;
    const int base = blockIdx.x * CHUNK;

    for (int i = tid; i < 1024; i += 256) sA[i] = 0;
    __syncthreads();

    int rj[EPT], cj[EPT];
    float wj[EPT];
#pragma unroll
    for (int j = 0; j < EPT; j++) {
        const int e = base + j * 256 + tid;
        if (e < NE) {
            rj[j] = rows[e];
            cj[j] = cols[e];
            const int k = (e >= 2 * E) ? 2 : (e >= E) ? 1 : 0;
            wj[j] = vals[e] * alpha[k];
            atomicAdd(&sA[rj[j] >> 7], 1);
        } else {
            rj[j] = -1;
        }
    }
    __syncthreads();

    // inclusive block scan of sA[0..1023] (ping-pong, ends in sA)
    {
        int* src = sA;
        int* dst = sB;
        for (int d = 1; d < 1024; d <<= 1) {
            for (int i = tid; i < 1024; i += 256) {
                int v = src[i];
                if (i >= d) v += src[i - d];
                dst[i] = v;
            }
            __syncthreads();
            int* t = src; src = dst; dst = t;
        }
    }

    // claim global space per non-empty bin; init local cursors
    for (int i = tid; i < NBUCK; i += 256) {
        const int excl = (i == 0) ? 0 : sA[i - 1];
        const int cnt = sA[i] - excl;
        lpos[i] = excl;
        if (cnt) lbase[i] = atomicAdd(&gcur[i], cnt);
    }
    __syncthreads();

    // place edges into stage, binned
#pragma unroll
    for (int j = 0; j < EPT; j++) {
        if (rj[j] >= 0) {
            const int b = rj[j] >> 7;
            const int p = atomicAdd(&lpos[b], 1);
            stage[p] = make_int2(((rj[j] & (RPB - 1)) << 17) | cj[j],
                                 __float_as_int(wj[j]));
            sbin[p] = (unsigned short)b;
        }
    }
    __syncthreads();

    // coalesced flush: consecutive p within a bin -> consecutive global dst
    const int total = sA[1023];
    for (int p = tid; p < total; p += 256) {
        const int b = sbin[p];
        const int excl = (b == 0) ? 0 : sA[b - 1];
        edgebuf[lbase[b] + (p - excl)] = stage[p];
    }
}

// ---------------------------------------------------------------------------
// K5: SpMM — one block per bucket, 128x32 fp32 accumulator in LDS.
// Half-wave (32 lanes = channels) per edge; ds_add_f32 is bank-conflict-free.
// Output written exactly once per row, bias fused. No global atomics.
// ---------------------------------------------------------------------------
__global__ __launch_bounds__(256) void spmm_c(const int2* __restrict__ edgebuf,
                                              const int* __restrict__ gstart,
                                              const float* __restrict__ y,
                                              const float* __restrict__ bias,
                                              float* __restrict__ out) {
    __shared__ float lacc[RPB * C];  // 16 KB
    __shared__ int2 sedge[ECH];      // 8 KB

    const int tid = threadIdx.x;
    const int b = blockIdx.x;
    const int s = gstart[b];
    const int n = gstart[b + 1] - s;

    for (int i = tid; i < RPB * C; i += 256) lacc[i] = 0.f;

    const int hw = tid >> 5;  // 8 half-waves per block
    const int c = tid & 31;

    for (int bb = 0; bb < n; bb += ECH) {
        const int m = min(ECH, n - bb);
        __syncthreads();  // protect sedge (and lacc zero on first iter)
        for (int i = tid; i < m; i += 256) sedge[i] = edgebuf[s + bb + i];
        __syncthreads();

        int i = hw;
        for (; i + 8 < m; i += 16) {  // 2 gathers in flight per half-wave
            const int2 e0 = sedge[i];
            const int2 e1 = sedge[i + 8];
            const float y0 = y[(e0.x & 0x1FFFF) * C + c];
            const float y1 = y[(e1.x & 0x1FFFF) * C + c];
            atomicAdd(&lacc[((e0.x >> 17) << 5) + c], __int_as_float(e0.y) * y0);
            atomicAdd(&lacc[((e1.x >> 17) << 5) + c], __int_as_float(e1.y) * y1);
        }
        for (; i < m; i += 8) {
            const int2 e0 = sedge[i];
            const float y0 = y[(e0.x & 0x1FFFF) * C + c];
            atomicAdd(&lacc[((e0.x >> 17) << 5) + c], __int_as_float(e0.y) * y0);
        }
    }
    __syncthreads();

    const int rows0 = b << 7;  // b * RPB
#pragma unroll
    for (int q = 0; q < 4; q++) {
        const int fi = (q * 256 + tid) * 4;
        const int row = rows0 + (fi >> 5);
        if (row < N_NODES) {
            const int c0 = fi & 31;
            float4 v = *(float4*)&lacc[fi];
            const float4 bv = *(const float4*)&bias[c0];
            v.x += bv.x; v.y += bv.y; v.z += bv.z; v.w += bv.w;
            *(float4*)(out + (size_t)row * C + c0) = v;
        }
    }
}

// ---------------------------------------------------------------------------
// Fallback path (atomic scatter) if workspace is too small.
// ---------------------------------------------------------------------------
__global__ __launch_bounds__(256) void scatter_edges(
    const float* __restrict__ vals, const int* __restrict__ rows,
    const int* __restrict__ cols, const float* __restrict__ alpha,
    const float* __restrict__ y, float* __restrict__ out_acc) {
    const int t = blockIdx.x * 256 + threadIdx.x;
    const int e = t >> 5;
    const int c = t & 31;
    if (e >= KH * E) return;
    const int k = (e >= 2 * E) ? 2 : (e >= E) ? 1 : 0;

    const float w = vals[e] * alpha[k];
    const int row = rows[e];
    const int col = cols[e];

    const float yv = y[(size_t)col * C + c];
    unsafeAtomicAdd(out_acc + (size_t)row * C + c, w * yv);
}

__global__ __launch_bounds__(256) void finalize_k(float* __restrict__ out,
                                                  const float* __restrict__ bias) {
    const int idx = (blockIdx.x * 256 + threadIdx.x) * 4;
    if (idx >= N_NODES * C) return;
    const int c0 = idx & (C - 1);
    float4 v = *(float4*)(out + idx);
    v.x += bias[c0 + 0];
    v.y += bias[c0 + 1];
    v.z += bias[c0 + 2];
    v.w += bias[c0 + 3];
    *(float4*)(out + idx) = v;
}

// ---------------------------------------------------------------------------
extern "C" void kernel_launch(void* const* d_in, const int* in_sizes, int n_in,
                              void* d_out, int out_size, void* d_ws, size_t ws_size,
                              hipStream_t stream) {
    const float* x         = (const float*)d_in[0];
    const float* edge_vals = (const float*)d_in[1];
    const float* W         = (const float*)d_in[2];
    const float* b         = (const float*)d_in[3];
    const float* alpha     = (const float*)d_in[4];
    const int*   edge_rows = (const int*)d_in[5];
    const int*   edge_cols = (const int*)d_in[6];
    float*       out       = (float*)d_out;

    // Workspace layout
    const size_t offY      = 0;                               // 12,800,000 B
    const size_t offEB     = (size_t)N_NODES * C * 4;         // edgebuf: 38,400,000 B
    const size_t offHist   = offEB + (size_t)NE * 8;          // 51,200,000
    const size_t offGstart = offHist + ((NBUCK * 4 + 255) & ~(size_t)255);
    const size_t offGcur   = offGstart + (((NBUCK + 1) * 4 + 255) & ~(size_t)255);
    const size_t need      = offGcur + (size_t)NBUCK * 4;     // ~51.21 MB

    float* y = (float*)((char*)d_ws + offY);

    gemm_xw<<<(N_NODES + 255) / 256, 256, 0, stream>>>(x, W, y);

    if (ws_size >= need) {
        int2* edgebuf = (int2*)((char*)d_ws + offEB);
        int*  hcnt    = (int*)((char*)d_ws + offHist);
        int*  gstart  = (int*)((char*)d_ws + offGstart);
        int*  gcur    = (int*)((char*)d_ws + offGcur);

        hipMemsetAsync(hcnt, 0, (size_t)NBUCK * 4, stream);

        hist_c<<<NCHUNK, 256, 0, stream>>>(edge_rows, hcnt);
        scan_c<<<1, 256, 0, stream>>>(hcnt, gstart, gcur);
        part_c<<<NCHUNK, 256, 0, stream>>>(edge_vals, edge_rows, edge_cols,
                                           alpha, gcur, edgebuf);
        spmm_c<<<NBUCK, 256, 0, stream>>>(edgebuf, gstart, y, b, out);
    } else {
        // Fallback: atomic scatter path
        hipMemsetAsync(out, 0, (size_t)N_NODES * C * sizeof(float), stream);
        const long long scatter_threads = (long long)KH * E * C;
        const int scatter_blocks = (int)((scatter_threads + 255) / 256);
        scatter_edges<<<scatter_blocks, 256, 0, stream>>>(
            edge_vals, edge_rows, edge_cols, alpha, y, out);
        finalize_k<<<(N_NODES * C / 4 + 255) / 256, 256, 0, stream>>>(out, b);
    }
}